// Round 1
// 1479.663 us; speedup vs baseline: 1.5024x; 1.5024x over previous
//
#include <hip/hip_runtime.h>
#include <math.h>

// RNNLayer: out[t] = tanh(x[t] @ Wx + b + h_{t-1} @ Wh), h_{-1} = h0
// S=128, B=128, D=1024. Inputs/outputs fp32.
//
// Phase 1: gemm_xp (fp32) writes xp = x@Wx + b into d_out.
// Phase 2: ONE persistent kernel, 128 WGs x 512 threads, runs all 128 steps.
//   - h @ Wh via MFMA 16x16x32 bf16; Wh register-resident as bf16 hi+lo.
//   - Cross-block h exchange through out[] using RELAXED AGENT-SCOPE ATOMICS
//     (per-line coherent, L2-bypassing). NO __threadfence anywhere.
//   - Round-6 restructure: blocks cover 16 rows x 64 cols (was 32), halving
//     block count (256->128), exchange volume (16->8 MB/step) and request
//     count. Grid barrier split into 8 INDEPENDENT per-batch-group barriers:
//     each block waits only on the 16 blocks of its own bt-group, polled by
//     16 threads (was: 256 threads x 256 blocks polling 256 global flags ->
//     ~32x less poll traffic at the coherence point, 16x fewer readers per
//     flag line, and no cross-group straggler coupling).
//   - Ordering: producer drains stores with s_waitcnt vmcnt(0) (asm, memory
//     clobber) before posting its flag; consumer spins on its group's flags,
//     then issues bypass loads (in-order issue after the spin + barrier).

#define DIM 1024
#define BATCH 128
#define SEQ 128
#define BD (BATCH * DIM)
#define NBLK 128
#define GRP 16        // blocks (column slabs) per batch-group
#define HSTR 1032     // hS row stride in ushorts (16B-aligned rows, bank spread)
#define FLAGSTR 16    // uints per flag slot (64 B) to avoid line contention

typedef __attribute__((ext_vector_type(8))) short bf16x8;
typedef __attribute__((ext_vector_type(4))) float f32x4;

static __device__ __forceinline__ unsigned short f2bf_rne(float f) {
    unsigned u = __builtin_bit_cast(unsigned, f);
    unsigned r = (u + 0x7FFFu + ((u >> 16) & 1u)) >> 16;
    return (unsigned short)r;
}
static __device__ __forceinline__ float bf2f(unsigned short h) {
    return __builtin_bit_cast(float, ((unsigned)h) << 16);
}

// ---------------------------------------------------------------------------
// Phase 1: fp32 GEMM, 64x64 tile (unchanged: ~471 us, 72 TF)
// ---------------------------------------------------------------------------
__global__ __launch_bounds__(256) void gemm_xp(
    const float* __restrict__ A, const float* __restrict__ W,
    const float* __restrict__ bias, float* __restrict__ C)
{
    __shared__ float As[32][68];
    __shared__ float Ws[32][68];

    const int tid  = threadIdx.x;
    const int trow = tid / 16;
    const int tcol = tid % 16;
    const int rowBase = blockIdx.y * 64;
    const int colBase = blockIdx.x * 64;

    const int lam = tid / 8;
    const int laf = tid % 8;
    const int lwk = tid / 16;
    const int lwf = tid % 16;

    float acc[4][4];
    #pragma unroll
    for (int i = 0; i < 4; ++i)
        #pragma unroll
        for (int j = 0; j < 4; ++j) acc[i][j] = 0.f;

    for (int k0 = 0; k0 < DIM; k0 += 32) {
        #pragma unroll
        for (int rr = 0; rr < 2; ++rr) {
            const int m = lam + rr * 32;
            const float4 v = *(const float4*)&A[(size_t)(rowBase + m) * DIM + k0 + laf * 4];
            As[laf * 4 + 0][m] = v.x;
            As[laf * 4 + 1][m] = v.y;
            As[laf * 4 + 2][m] = v.z;
            As[laf * 4 + 3][m] = v.w;
        }
        #pragma unroll
        for (int rr = 0; rr < 2; ++rr) {
            const int k = lwk + rr * 16;
            *(float4*)&Ws[k][lwf * 4] =
                *(const float4*)&W[(size_t)(k0 + k) * DIM + colBase + lwf * 4];
        }
        __syncthreads();

        #pragma unroll
        for (int kk = 0; kk < 32; ++kk) {
            const float4 a4 = *(const float4*)&As[kk][trow * 4];
            const float4 w4 = *(const float4*)&Ws[kk][tcol * 4];
            const float av[4] = {a4.x, a4.y, a4.z, a4.w};
            const float wv[4] = {w4.x, w4.y, w4.z, w4.w};
            #pragma unroll
            for (int i = 0; i < 4; ++i)
                #pragma unroll
                for (int j = 0; j < 4; ++j)
                    acc[i][j] += av[i] * wv[j];
        }
        __syncthreads();
    }

    #pragma unroll
    for (int i = 0; i < 4; ++i) {
        const int row = rowBase + trow * 4 + i;
        const int col = colBase + tcol * 4;
        const float4 bv = *(const float4*)&bias[col];
        float4 o;
        o.x = acc[i][0] + bv.x;
        o.y = acc[i][1] + bv.y;
        o.z = acc[i][2] + bv.z;
        o.w = acc[i][3] + bv.w;
        *(float4*)&C[(size_t)row * DIM + col] = o;
    }
}

// ---------------------------------------------------------------------------
// Phase 2: persistent MFMA scan, fence-free coherence, per-group barriers.
// Block bid: bt = bid>>4 (16 batch rows), ct = bid&15 (64-col slab).
// Wave w (of 8): 16-col tile (w>>1), k-half (w&1). Wh bf16 hi/lo in regs
// (same 128 VGPRs/thread of Wh as the 256-thread version).
// ---------------------------------------------------------------------------
__global__ __launch_bounds__(512) void rnn_scan(
    const float* __restrict__ h0,
    const float* __restrict__ Wh,
    float* out,
    unsigned* flags)
{
    __shared__ unsigned short hS[16 * HSTR];   // 33 KB bf16 h tile (16 x 1024)
    __shared__ f32x4 redS[256];                // 4 KB k-half exchange

    const int tid = threadIdx.x;
    const int bid = blockIdx.x;
    const int bt  = bid >> 4;
    const int ct  = bid & 15;
    const int B0  = bt * 16;
    const int Cb  = ct * 64;

    const int w = tid >> 6;          // 0..7
    const int l = tid & 63;
    const int n = l & 15;
    const int q = l >> 4;
    const int cb = Cb + (w >> 1) * 16;
    const int K0 = (w & 1) * 512;

    // ---- resident Wh B-fragments (bf16 hi + lo), loaded once ----
    bf16x8 Bhi[16], Blo[16];
    #pragma unroll
    for (int s = 0; s < 16; ++s) {
        bf16x8 hi, lo;
        #pragma unroll
        for (int j = 0; j < 8; ++j) {
            const int k = K0 + 32 * s + q * 8 + j;
            const float wv = Wh[(size_t)k * DIM + cb + n];
            const unsigned short h16 = f2bf_rne(wv);
            hi[j] = (short)h16;
            lo[j] = (short)f2bf_rne(wv - bf2f(h16));
        }
        Bhi[s] = hi;
        Blo[s] = lo;
    }

    const int sr = tid >> 5;    // staging: row 0..15 (32 threads per row)
    const int su = tid & 31;    // staging: ulong lane within row

    for (int t = 0; t < SEQ; ++t) {
        const float* hsrc = (t == 0) ? (h0 + (size_t)B0 * DIM)
                                     : (out + (size_t)(t - 1) * BD + (size_t)B0 * DIM);
        float* outT = out + (size_t)t * BD;

        // ---- stage h tile: coherent 8B bypass loads -> bf16 -> LDS ----
        {
            const unsigned long long* srow =
                (const unsigned long long*)(hsrc + (size_t)sr * DIM);
            unsigned short* drow = &hS[sr * HSTR];
            #pragma unroll
            for (int i = 0; i < 16; ++i) {
                const unsigned long long v = __hip_atomic_load(
                    srow + su + 32 * i, __ATOMIC_RELAXED, __HIP_MEMORY_SCOPE_AGENT);
                const float f0 = __builtin_bit_cast(float, (unsigned)(v & 0xFFFFFFFFull));
                const float f1 = __builtin_bit_cast(float, (unsigned)(v >> 32));
                const unsigned pk =
                    (unsigned)f2bf_rne(f0) | ((unsigned)f2bf_rne(f1) << 16);
                *(unsigned*)(drow + 2 * (su + 32 * i)) = pk;
            }
        }

        // ---- xp prefetch (even waves; same thread rewrites these) ----
        float xpv[4];
        if (!(w & 1)) {
            #pragma unroll
            for (int i = 0; i < 4; ++i)
                xpv[i] = __builtin_nontemporal_load(
                    &outT[(size_t)(B0 + q * 4 + i) * DIM + cb + n]);
        }

        __syncthreads();

        // ---- MFMA over this wave's k-half ----
        f32x4 acc = {0.f, 0.f, 0.f, 0.f};
        {
            const unsigned short* hrow = &hS[(l & 15) * HSTR + K0];
            #pragma unroll
            for (int s = 0; s < 16; ++s) {
                const bf16x8 a = *(const bf16x8*)(hrow + 32 * s + 8 * q);
                acc = __builtin_amdgcn_mfma_f32_16x16x32_bf16(a, Bhi[s], acc, 0, 0, 0);
                acc = __builtin_amdgcn_mfma_f32_16x16x32_bf16(a, Blo[s], acc, 0, 0, 0);
            }
        }

        // ---- reduce k-halves: odd waves hand partials to even waves ----
        if (w & 1) redS[(w >> 1) * 64 + l] = acc;
        __syncthreads();

        if (!(w & 1)) {
            const f32x4 p = redS[(w >> 1) * 64 + l];
            // C/D layout: col = lane&15, row = q*4 + reg
            #pragma unroll
            for (int i = 0; i < 4; ++i) {
                const float v = tanhf(acc[i] + p[i] + xpv[i]);
                // coherent write-through store: visible at IC, no fence needed
                __hip_atomic_store(&outT[(size_t)(B0 + q * 4 + i) * DIM + cb + n],
                                   v, __ATOMIC_RELAXED, __HIP_MEMORY_SCOPE_AGENT);
            }
        }

        // ---- fence-free PER-GROUP barrier (16 blocks sharing bt) ----
        if (t < SEQ - 1) {
            // drain my wave's stores to the coherence point before arriving
            asm volatile("s_waitcnt vmcnt(0)" ::: "memory");
            __syncthreads();   // all waves' stores drained
            if (tid == 0)
                __hip_atomic_store(&flags[bid * FLAGSTR], (unsigned)(t + 1),
                                   __ATOMIC_RELAXED, __HIP_MEMORY_SCOPE_AGENT);
            // threads 0..15 each watch one block of this bt-group
            if (tid < GRP) {
                const unsigned* slot = &flags[(bt * GRP + tid) * FLAGSTR];
                while (__hip_atomic_load(slot, __ATOMIC_RELAXED,
                                         __HIP_MEMORY_SCOPE_AGENT) < (unsigned)(t + 1))
                    __builtin_amdgcn_s_sleep(2);
            }
            __syncthreads();
        }
    }
}

// ---------------------------------------------------------------------------
extern "C" void kernel_launch(void* const* d_in, const int* in_sizes, int n_in,
                              void* d_out, int out_size, void* d_ws, size_t ws_size,
                              hipStream_t stream) {
    const float* x  = (const float*)d_in[0];   // [S,B,D]
    const float* h0 = (const float*)d_in[1];   // [B,D]
    const float* Wx = (const float*)d_in[2];   // [D,D]
    const float* Wh = (const float*)d_in[3];   // [D,D]
    const float* b  = (const float*)d_in[4];   // [D]
    float* out = (float*)d_out;                // [S,B,D]
    unsigned* flags = (unsigned*)d_ws;         // 128 slots x 64 B

    hipMemsetAsync(d_ws, 0, NBLK * FLAGSTR * sizeof(unsigned), stream);

    gemm_xp<<<dim3(DIM / 64, (SEQ * BATCH) / 64), 256, 0, stream>>>(x, Wx, b, out);

    rnn_scan<<<dim3(NBLK), dim3(512), 0, stream>>>(h0, Wh, out, flags);
}

// Round 2
// 1270.070 us; speedup vs baseline: 1.7503x; 1.1650x over previous
//
#include <hip/hip_runtime.h>
#include <math.h>

// RNNLayer: out[t] = tanh(x[t] @ Wx + b + h_{t-1} @ Wh), h_{-1} = h0
// S=128, B=128, D=1024. Inputs/outputs fp32.
//
// Phase 1 (round 7): persistent MFMA kernel xp_pers, 256 WGs x 512 threads.
//   xp[t] = x[t]@Wx + b is 128 independent GEMMs of the exact shape phase 2
//   runs per step -> reuse phase-2's block structure: 16 rows x 64 cols,
//   8 waves (4 col-tiles x 2 k-halves), Wx register-resident bf16 hi+lo
//   loaded ONCE per block (vs per-block reload in a standard GEMM grid).
//   x staged as bf16 hi+lo (3 MFMA combos: hh, lh, hl) so phase-1 error is
//   ~1e-4, keeping total absmax at the phase-2-dominated 0.0078.
//   Grid = 2 t-halves x 8 row-groups x 16 col-slabs; no flags, no atomics.
// Phase 2: persistent scan, 128 WGs x 512 threads (unchanged from round 6).
//   - h @ Wh via MFMA 16x16x32 bf16; Wh register-resident as bf16 hi+lo.
//   - Cross-block h exchange through out[] using RELAXED AGENT-SCOPE ATOMICS
//     (per-line coherent, L2-bypassing). NO __threadfence anywhere.
//   - Per-batch-group barriers (16 blocks, 16 polling threads).
//   - Ordering: producer drains stores with s_waitcnt vmcnt(0) before
//     posting its flag; consumer spins on its group's flags.

#define DIM 1024
#define BATCH 128
#define SEQ 128
#define BD (BATCH * DIM)
#define NBLK 128
#define GRP 16        // blocks (column slabs) per batch-group
#define HSTR 1032     // LDS row stride in ushorts (16B-aligned rows, bank spread)
#define FLAGSTR 16    // uints per flag slot (64 B) to avoid line contention
#define XNB 256       // phase-1 persistent blocks

typedef __attribute__((ext_vector_type(8))) short bf16x8;
typedef __attribute__((ext_vector_type(4))) float f32x4;

static __device__ __forceinline__ unsigned short f2bf_rne(float f) {
    unsigned u = __builtin_bit_cast(unsigned, f);
    unsigned r = (u + 0x7FFFu + ((u >> 16) & 1u)) >> 16;
    return (unsigned short)r;
}
static __device__ __forceinline__ float bf2f(unsigned short h) {
    return __builtin_bit_cast(float, ((unsigned)h) << 16);
}

// ---------------------------------------------------------------------------
// Phase 1: persistent MFMA xp GEMM.
// Block bid: tg = bid>>7 (t-half), bt = (bid>>4)&7 (16 batch rows),
//            ct = bid&15 (64-col slab). Wave w: col-tile (w>>1), k-half (w&1).
// ---------------------------------------------------------------------------
__global__ __launch_bounds__(512) void xp_pers(
    const float* __restrict__ x,
    const float* __restrict__ Wx,
    const float* __restrict__ bias,
    float* __restrict__ out)
{
    __shared__ unsigned short hHi[16 * HSTR];   // 33 KB x-tile hi
    __shared__ unsigned short hLo[16 * HSTR];   // 33 KB x-tile lo
    __shared__ f32x4 redS[256];                 // 4 KB k-half exchange

    const int tid = threadIdx.x;
    const int bid = blockIdx.x;
    const int tg  = bid >> 7;
    const int bt  = (bid >> 4) & 7;
    const int ct  = bid & 15;
    const int B0  = bt * 16;
    const int Cb  = ct * 64;

    const int w = tid >> 6;          // 0..7
    const int l = tid & 63;
    const int n = l & 15;
    const int q = l >> 4;
    const int cb = Cb + (w >> 1) * 16;
    const int K0 = (w & 1) * 512;

    // ---- resident Wx B-fragments (bf16 hi + lo), loaded once ----
    bf16x8 Bhi[16], Blo[16];
    #pragma unroll
    for (int s = 0; s < 16; ++s) {
        bf16x8 hi, lo;
        #pragma unroll
        for (int j = 0; j < 8; ++j) {
            const int k = K0 + 32 * s + q * 8 + j;
            const float wv = Wx[(size_t)k * DIM + cb + n];
            const unsigned short h16 = f2bf_rne(wv);
            hi[j] = (short)h16;
            lo[j] = (short)f2bf_rne(wv - bf2f(h16));
        }
        Bhi[s] = hi;
        Blo[s] = lo;
    }

    const float bv = bias[cb + n];   // per-thread bias (col is fixed)

    const int sr = tid >> 5;    // staging: row 0..15 (32 threads per row)
    const int su = tid & 31;    // staging: ulong lane within row

    for (int tt = 0; tt < SEQ / 2; ++tt) {
        const int t = tg * (SEQ / 2) + tt;
        const float* xT = x + (size_t)t * BD + (size_t)B0 * DIM;
        float* outT = out + (size_t)t * BD;

        // ---- stage x tile: fp32 -> bf16 hi + lo -> LDS ----
        {
            const unsigned long long* srow =
                (const unsigned long long*)(xT + (size_t)sr * DIM);
            unsigned short* dh = &hHi[sr * HSTR];
            unsigned short* dl = &hLo[sr * HSTR];
            #pragma unroll
            for (int i = 0; i < 16; ++i) {
                const unsigned long long v = srow[su + 32 * i];
                const float f0 = __builtin_bit_cast(float, (unsigned)(v & 0xFFFFFFFFull));
                const float f1 = __builtin_bit_cast(float, (unsigned)(v >> 32));
                const unsigned short h0 = f2bf_rne(f0);
                const unsigned short h1 = f2bf_rne(f1);
                const unsigned short l0 = f2bf_rne(f0 - bf2f(h0));
                const unsigned short l1 = f2bf_rne(f1 - bf2f(h1));
                *(unsigned*)(dh + 2 * (su + 32 * i)) =
                    (unsigned)h0 | ((unsigned)h1 << 16);
                *(unsigned*)(dl + 2 * (su + 32 * i)) =
                    (unsigned)l0 | ((unsigned)l1 << 16);
            }
        }

        __syncthreads();

        // ---- MFMA over this wave's k-half: hh + lh + hl ----
        f32x4 acc = {0.f, 0.f, 0.f, 0.f};
        {
            const unsigned short* rh = &hHi[(l & 15) * HSTR + K0];
            const unsigned short* rl = &hLo[(l & 15) * HSTR + K0];
            #pragma unroll
            for (int s = 0; s < 16; ++s) {
                const bf16x8 ah = *(const bf16x8*)(rh + 32 * s + 8 * q);
                const bf16x8 al = *(const bf16x8*)(rl + 32 * s + 8 * q);
                acc = __builtin_amdgcn_mfma_f32_16x16x32_bf16(ah, Bhi[s], acc, 0, 0, 0);
                acc = __builtin_amdgcn_mfma_f32_16x16x32_bf16(al, Bhi[s], acc, 0, 0, 0);
                acc = __builtin_amdgcn_mfma_f32_16x16x32_bf16(ah, Blo[s], acc, 0, 0, 0);
            }
        }

        // ---- reduce k-halves: odd waves hand partials to even waves ----
        if (w & 1) redS[(w >> 1) * 64 + l] = acc;
        __syncthreads();

        if (!(w & 1)) {
            const f32x4 p = redS[(w >> 1) * 64 + l];
            // C/D layout: col = lane&15, row = q*4 + reg
            #pragma unroll
            for (int i = 0; i < 4; ++i)
                outT[(size_t)(B0 + q * 4 + i) * DIM + cb + n] = acc[i] + p[i] + bv;
        }
        // next iteration's staging is fenced by the first __syncthreads();
        // all hHi/hLo reads of this iter precede the redS barrier above.
    }
}

// ---------------------------------------------------------------------------
// Phase 2: persistent MFMA scan, fence-free coherence, per-group barriers.
// Block bid: bt = bid>>4 (16 batch rows), ct = bid&15 (64-col slab).
// Wave w (of 8): 16-col tile (w>>1), k-half (w&1). Wh bf16 hi/lo in regs.
// ---------------------------------------------------------------------------
__global__ __launch_bounds__(512) void rnn_scan(
    const float* __restrict__ h0,
    const float* __restrict__ Wh,
    float* out,
    unsigned* flags)
{
    __shared__ unsigned short hS[16 * HSTR];   // 33 KB bf16 h tile (16 x 1024)
    __shared__ f32x4 redS[256];                // 4 KB k-half exchange

    const int tid = threadIdx.x;
    const int bid = blockIdx.x;
    const int bt  = bid >> 4;
    const int ct  = bid & 15;
    const int B0  = bt * 16;
    const int Cb  = ct * 64;

    const int w = tid >> 6;          // 0..7
    const int l = tid & 63;
    const int n = l & 15;
    const int q = l >> 4;
    const int cb = Cb + (w >> 1) * 16;
    const int K0 = (w & 1) * 512;

    // ---- resident Wh B-fragments (bf16 hi + lo), loaded once ----
    bf16x8 Bhi[16], Blo[16];
    #pragma unroll
    for (int s = 0; s < 16; ++s) {
        bf16x8 hi, lo;
        #pragma unroll
        for (int j = 0; j < 8; ++j) {
            const int k = K0 + 32 * s + q * 8 + j;
            const float wv = Wh[(size_t)k * DIM + cb + n];
            const unsigned short h16 = f2bf_rne(wv);
            hi[j] = (short)h16;
            lo[j] = (short)f2bf_rne(wv - bf2f(h16));
        }
        Bhi[s] = hi;
        Blo[s] = lo;
    }

    const int sr = tid >> 5;    // staging: row 0..15 (32 threads per row)
    const int su = tid & 31;    // staging: ulong lane within row

    for (int t = 0; t < SEQ; ++t) {
        const float* hsrc = (t == 0) ? (h0 + (size_t)B0 * DIM)
                                     : (out + (size_t)(t - 1) * BD + (size_t)B0 * DIM);
        float* outT = out + (size_t)t * BD;

        // ---- stage h tile: coherent 8B bypass loads -> bf16 -> LDS ----
        {
            const unsigned long long* srow =
                (const unsigned long long*)(hsrc + (size_t)sr * DIM);
            unsigned short* drow = &hS[sr * HSTR];
            #pragma unroll
            for (int i = 0; i < 16; ++i) {
                const unsigned long long v = __hip_atomic_load(
                    srow + su + 32 * i, __ATOMIC_RELAXED, __HIP_MEMORY_SCOPE_AGENT);
                const float f0 = __builtin_bit_cast(float, (unsigned)(v & 0xFFFFFFFFull));
                const float f1 = __builtin_bit_cast(float, (unsigned)(v >> 32));
                const unsigned pk =
                    (unsigned)f2bf_rne(f0) | ((unsigned)f2bf_rne(f1) << 16);
                *(unsigned*)(drow + 2 * (su + 32 * i)) = pk;
            }
        }

        // ---- xp prefetch (even waves; same thread rewrites these) ----
        float xpv[4];
        if (!(w & 1)) {
            #pragma unroll
            for (int i = 0; i < 4; ++i)
                xpv[i] = __builtin_nontemporal_load(
                    &outT[(size_t)(B0 + q * 4 + i) * DIM + cb + n]);
        }

        __syncthreads();

        // ---- MFMA over this wave's k-half ----
        f32x4 acc = {0.f, 0.f, 0.f, 0.f};
        {
            const unsigned short* hrow = &hS[(l & 15) * HSTR + K0];
            #pragma unroll
            for (int s = 0; s < 16; ++s) {
                const bf16x8 a = *(const bf16x8*)(hrow + 32 * s + 8 * q);
                acc = __builtin_amdgcn_mfma_f32_16x16x32_bf16(a, Bhi[s], acc, 0, 0, 0);
                acc = __builtin_amdgcn_mfma_f32_16x16x32_bf16(a, Blo[s], acc, 0, 0, 0);
            }
        }

        // ---- reduce k-halves: odd waves hand partials to even waves ----
        if (w & 1) redS[(w >> 1) * 64 + l] = acc;
        __syncthreads();

        if (!(w & 1)) {
            const f32x4 p = redS[(w >> 1) * 64 + l];
            // C/D layout: col = lane&15, row = q*4 + reg
            #pragma unroll
            for (int i = 0; i < 4; ++i) {
                const float v = tanhf(acc[i] + p[i] + xpv[i]);
                // coherent write-through store: visible at IC, no fence needed
                __hip_atomic_store(&outT[(size_t)(B0 + q * 4 + i) * DIM + cb + n],
                                   v, __ATOMIC_RELAXED, __HIP_MEMORY_SCOPE_AGENT);
            }
        }

        // ---- fence-free PER-GROUP barrier (16 blocks sharing bt) ----
        if (t < SEQ - 1) {
            // drain my wave's stores to the coherence point before arriving
            asm volatile("s_waitcnt vmcnt(0)" ::: "memory");
            __syncthreads();   // all waves' stores drained
            if (tid == 0)
                __hip_atomic_store(&flags[bid * FLAGSTR], (unsigned)(t + 1),
                                   __ATOMIC_RELAXED, __HIP_MEMORY_SCOPE_AGENT);
            // threads 0..15 each watch one block of this bt-group
            if (tid < GRP) {
                const unsigned* slot = &flags[(bt * GRP + tid) * FLAGSTR];
                while (__hip_atomic_load(slot, __ATOMIC_RELAXED,
                                         __HIP_MEMORY_SCOPE_AGENT) < (unsigned)(t + 1))
                    __builtin_amdgcn_s_sleep(2);
            }
            __syncthreads();
        }
    }
}

// ---------------------------------------------------------------------------
extern "C" void kernel_launch(void* const* d_in, const int* in_sizes, int n_in,
                              void* d_out, int out_size, void* d_ws, size_t ws_size,
                              hipStream_t stream) {
    const float* x  = (const float*)d_in[0];   // [S,B,D]
    const float* h0 = (const float*)d_in[1];   // [B,D]
    const float* Wx = (const float*)d_in[2];   // [D,D]
    const float* Wh = (const float*)d_in[3];   // [D,D]
    const float* b  = (const float*)d_in[4];   // [D]
    float* out = (float*)d_out;                // [S,B,D]
    unsigned* flags = (unsigned*)d_ws;         // 128 slots x 64 B

    hipMemsetAsync(d_ws, 0, NBLK * FLAGSTR * sizeof(unsigned), stream);

    xp_pers<<<dim3(XNB), dim3(512), 0, stream>>>(x, Wx, b, out);

    rnn_scan<<<dim3(NBLK), dim3(512), 0, stream>>>(h0, Wh, out, flags);
}

// Round 3
// 800.603 us; speedup vs baseline: 2.7766x; 1.5864x over previous
//
#include <hip/hip_runtime.h>
#include <math.h>

// RNNLayer: out[t] = tanh(x[t] @ Wx + b + h_{t-1} @ Wh), h_{-1} = h0
// S=128, B=128, D=1024. Inputs/outputs fp32.
//
// Phase 1 (round 8): persistent MFMA xp kernel, software-pipelined:
//   next-step x loads issued into registers BEFORE the MFMA cluster,
//   converted + LDS-written after the redS sync (T14 async-STAGE split).
//   Single LDS buffer is safe: all MFMA reads complete before the mid-sync.
// Phase 2 (round 8): persistent scan with bf16 SIDE-CHANNEL exchange.
//   - Producers pack h-rows to bf16 and write ONE 8B bypass store per even
//     thread into hX (workspace), col-major [1024 cols][16 rows] per group,
//     double-buffered by t-parity. out[] is now a plain nontemporal fp32
//     store (nobody reads it cross-block; drains at L2 speed, not IC).
//   - Consumers stage 8 x 8B bypass loads (half the old bytes/requests) and
//     transpose 4x4 bf16 blocks in-register into row-major LDS; the whole
//     f2bf conversion chain on the consumer side is gone.
//   - Parity double-buffer is race-free: flags are posted AFTER staging +
//     stores, so "all flags >= t" implies all blocks finished READING slab
//     (t-1)&1; only then can anyone write it again at t+1.
//   - Ordering unchanged: producer drains with s_waitcnt vmcnt(0) before
//     posting its flag; consumers spin on their group's 16 flags.
// Workspace: flags 8 KB @ 0, hX 512 KB @ 8192. Total 520 KB of d_ws.

#define DIM 1024
#define BATCH 128
#define SEQ 128
#define BD (BATCH * DIM)
#define NBLK 128
#define GRP 16        // blocks (column slabs) per batch-group
#define HSTR 1032     // LDS row stride in ushorts (16B-aligned rows, bank spread)
#define FLAGSTR 16    // uints per flag slot (64 B) to avoid line contention
#define XNB 256       // phase-1 persistent blocks
#define HXGRP 16384   // ushorts per group slab (16 rows x 1024 cols)

typedef __attribute__((ext_vector_type(8))) short bf16x8;
typedef __attribute__((ext_vector_type(4))) float f32x4;

static __device__ __forceinline__ unsigned short f2bf_rne(float f) {
    unsigned u = __builtin_bit_cast(unsigned, f);
    unsigned r = (u + 0x7FFFu + ((u >> 16) & 1u)) >> 16;
    return (unsigned short)r;
}
static __device__ __forceinline__ float bf2f(unsigned short h) {
    return __builtin_bit_cast(float, ((unsigned)h) << 16);
}

// ---------------------------------------------------------------------------
// Phase 1: persistent MFMA xp GEMM, software-pipelined.
// Block bid: tg = bid>>7 (t-half), bt = (bid>>4)&7 (16 batch rows),
//            ct = bid&15 (64-col slab). Wave w: col-tile (w>>1), k-half (w&1).
// ---------------------------------------------------------------------------
__global__ __launch_bounds__(512) void xp_pers(
    const float* __restrict__ x,
    const float* __restrict__ Wx,
    const float* __restrict__ bias,
    float* __restrict__ out)
{
    __shared__ unsigned short hHi[16 * HSTR];   // 33 KB x-tile hi
    __shared__ unsigned short hLo[16 * HSTR];   // 33 KB x-tile lo
    __shared__ f32x4 redS[256];                 // 4 KB k-half exchange

    const int tid = threadIdx.x;
    const int bid = blockIdx.x;
    const int tg  = bid >> 7;
    const int bt  = (bid >> 4) & 7;
    const int ct  = bid & 15;
    const int B0  = bt * 16;
    const int Cb  = ct * 64;
    const int NT  = SEQ / 2;

    const int w = tid >> 6;          // 0..7
    const int l = tid & 63;
    const int n = l & 15;
    const int q = l >> 4;
    const int cb = Cb + (w >> 1) * 16;
    const int K0 = (w & 1) * 512;

    // ---- resident Wx B-fragments (bf16 hi + lo), loaded once ----
    bf16x8 Bhi[16], Blo[16];
    #pragma unroll
    for (int s = 0; s < 16; ++s) {
        bf16x8 hi, lo;
        #pragma unroll
        for (int j = 0; j < 8; ++j) {
            const int k = K0 + 32 * s + q * 8 + j;
            const float wv = Wx[(size_t)k * DIM + cb + n];
            const unsigned short h16 = f2bf_rne(wv);
            hi[j] = (short)h16;
            lo[j] = (short)f2bf_rne(wv - bf2f(h16));
        }
        Bhi[s] = hi;
        Blo[s] = lo;
    }

    const float bv = bias[cb + n];   // per-thread bias (col is fixed)

    const int sr = tid >> 5;    // staging: row 0..15 (32 threads per row)
    const int su = tid & 31;    // staging: ulong lane within row

    // ---- prologue: stage step 0 fully ----
    {
        const float* xT = x + (size_t)(tg * NT) * BD + (size_t)B0 * DIM;
        const unsigned long long* srow =
            (const unsigned long long*)(xT + (size_t)sr * DIM);
        unsigned short* dh = &hHi[sr * HSTR];
        unsigned short* dl = &hLo[sr * HSTR];
        #pragma unroll
        for (int i = 0; i < 16; ++i) {
            const unsigned long long v = srow[su + 32 * i];
            const float f0 = __builtin_bit_cast(float, (unsigned)(v & 0xFFFFFFFFull));
            const float f1 = __builtin_bit_cast(float, (unsigned)(v >> 32));
            const unsigned short h0 = f2bf_rne(f0);
            const unsigned short h1 = f2bf_rne(f1);
            const unsigned short l0 = f2bf_rne(f0 - bf2f(h0));
            const unsigned short l1 = f2bf_rne(f1 - bf2f(h1));
            *(unsigned*)(dh + 2 * (su + 32 * i)) = (unsigned)h0 | ((unsigned)h1 << 16);
            *(unsigned*)(dl + 2 * (su + 32 * i)) = (unsigned)l0 | ((unsigned)l1 << 16);
        }
    }

    for (int tt = 0; tt < NT; ++tt) {
        const int t = tg * NT + tt;
        float* outT = out + (size_t)t * BD;

        __syncthreads();   // LDS tile for step tt ready; redS from prev consumed

        // ---- issue NEXT step's x loads into registers (latency hides under MFMA)
        unsigned long long xr[16];
        if (tt + 1 < NT) {
            const float* xN = x + (size_t)(t + 1) * BD + (size_t)B0 * DIM;
            const unsigned long long* srow =
                (const unsigned long long*)(xN + (size_t)sr * DIM);
            #pragma unroll
            for (int i = 0; i < 16; ++i) xr[i] = srow[su + 32 * i];
        }

        // ---- MFMA over this wave's k-half: hh + lh + hl ----
        f32x4 acc = {0.f, 0.f, 0.f, 0.f};
        {
            const unsigned short* rh = &hHi[(l & 15) * HSTR + K0];
            const unsigned short* rl = &hLo[(l & 15) * HSTR + K0];
            #pragma unroll
            for (int s = 0; s < 16; ++s) {
                const bf16x8 ah = *(const bf16x8*)(rh + 32 * s + 8 * q);
                const bf16x8 al = *(const bf16x8*)(rl + 32 * s + 8 * q);
                acc = __builtin_amdgcn_mfma_f32_16x16x32_bf16(ah, Bhi[s], acc, 0, 0, 0);
                acc = __builtin_amdgcn_mfma_f32_16x16x32_bf16(al, Bhi[s], acc, 0, 0, 0);
                acc = __builtin_amdgcn_mfma_f32_16x16x32_bf16(ah, Blo[s], acc, 0, 0, 0);
            }
        }

        // ---- reduce k-halves ----
        if (w & 1) redS[(w >> 1) * 64 + l] = acc;
        __syncthreads();   // after this, ALL MFMA reads of the LDS tile are done

        if (!(w & 1)) {
            const f32x4 p = redS[(w >> 1) * 64 + l];
            #pragma unroll
            for (int i = 0; i < 4; ++i)
                outT[(size_t)(B0 + q * 4 + i) * DIM + cb + n] = acc[i] + p[i] + bv;
        }

        // ---- convert + write NEXT step's tile into the (now free) LDS buffer
        if (tt + 1 < NT) {
            unsigned short* dh = &hHi[sr * HSTR];
            unsigned short* dl = &hLo[sr * HSTR];
            #pragma unroll
            for (int i = 0; i < 16; ++i) {
                const unsigned long long v = xr[i];
                const float f0 = __builtin_bit_cast(float, (unsigned)(v & 0xFFFFFFFFull));
                const float f1 = __builtin_bit_cast(float, (unsigned)(v >> 32));
                const unsigned short h0 = f2bf_rne(f0);
                const unsigned short h1 = f2bf_rne(f1);
                const unsigned short l0 = f2bf_rne(f0 - bf2f(h0));
                const unsigned short l1 = f2bf_rne(f1 - bf2f(h1));
                *(unsigned*)(dh + 2 * (su + 32 * i)) = (unsigned)h0 | ((unsigned)h1 << 16);
                *(unsigned*)(dl + 2 * (su + 32 * i)) = (unsigned)l0 | ((unsigned)l1 << 16);
            }
        }
    }
}

// ---------------------------------------------------------------------------
// Phase 2: persistent MFMA scan, bf16 side-channel exchange, per-group
// barriers. Block bid: bt = bid>>4 (16 batch rows), ct = bid&15 (64-col slab).
// Wave w (of 8): 16-col tile (w>>1), k-half (w&1). Wh bf16 hi/lo in regs.
// hX layout: [slab 0/1][group bt][col 0..1023][row 0..15] bf16.
// ---------------------------------------------------------------------------
__global__ __launch_bounds__(512) void rnn_scan(
    const float* __restrict__ h0,
    const float* __restrict__ Wh,
    float* out,
    unsigned* flags,
    unsigned short* hX)
{
    __shared__ unsigned short hS[16 * HSTR];   // 33 KB bf16 h tile (16 x 1024)
    __shared__ f32x4 redS[256];                // 4 KB k-half exchange

    const int tid = threadIdx.x;
    const int bid = blockIdx.x;
    const int bt  = bid >> 4;
    const int ct  = bid & 15;
    const int B0  = bt * 16;
    const int Cb  = ct * 64;

    const int w = tid >> 6;          // 0..7
    const int l = tid & 63;
    const int n = l & 15;
    const int q = l >> 4;
    const int cb = Cb + (w >> 1) * 16;
    const int K0 = (w & 1) * 512;

    // ---- resident Wh B-fragments (bf16 hi + lo), loaded once ----
    bf16x8 Bhi[16], Blo[16];
    #pragma unroll
    for (int s = 0; s < 16; ++s) {
        bf16x8 hi, lo;
        #pragma unroll
        for (int j = 0; j < 8; ++j) {
            const int k = K0 + 32 * s + q * 8 + j;
            const float wv = Wh[(size_t)k * DIM + cb + n];
            const unsigned short h16 = f2bf_rne(wv);
            hi[j] = (short)h16;
            lo[j] = (short)f2bf_rne(wv - bf2f(h16));
        }
        Bhi[s] = hi;
        Blo[s] = lo;
    }

    const int sr = tid >> 5;    // t==0 staging: row, 32 threads per row
    const int su = tid & 31;    // t==0 staging: ulong lane within row
    const int qq = tid & 3;     // t>0 staging: row quad
    const int c0 = (tid >> 2) & 127;   // t>0 staging: col-group base

    for (int t = 0; t < SEQ; ++t) {
        float* outT = out + (size_t)t * BD;

        // ---- xp prefetch first (independent of h exchange; longest latency)
        float xpv[4];
        if (!(w & 1)) {
            #pragma unroll
            for (int i = 0; i < 4; ++i)
                xpv[i] = __builtin_nontemporal_load(
                    &outT[(size_t)(B0 + q * 4 + i) * DIM + cb + n]);
        }

        // ---- stage h tile into row-major LDS ----
        if (t == 0) {
            const float* hsrc = h0 + (size_t)B0 * DIM;
            const unsigned long long* srow =
                (const unsigned long long*)(hsrc + (size_t)sr * DIM);
            unsigned short* drow = &hS[sr * HSTR];
            #pragma unroll
            for (int i = 0; i < 16; ++i) {
                const unsigned long long v = srow[su + 32 * i];
                const float f0 = __builtin_bit_cast(float, (unsigned)(v & 0xFFFFFFFFull));
                const float f1 = __builtin_bit_cast(float, (unsigned)(v >> 32));
                const unsigned pk =
                    (unsigned)f2bf_rne(f0) | ((unsigned)f2bf_rne(f1) << 16);
                *(unsigned*)(drow + 2 * (su + 32 * i)) = pk;
            }
        } else {
            // bf16 side-channel: 8 x 8B bypass loads + in-register 4x4 transpose
            const unsigned short* gX = hX + (size_t)((t - 1) & 1) * (8 * HXGRP)
                                          + (size_t)bt * HXGRP;
            #pragma unroll
            for (int half = 0; half < 2; ++half) {
                const int cp = c0 + half * 128;    // col-group: cols 4cp..4cp+3
                unsigned long long L[4];
                #pragma unroll
                for (int cc = 0; cc < 4; ++cc)
                    L[cc] = __hip_atomic_load(
                        (const unsigned long long*)(gX + (size_t)(4 * cp + cc) * 16 + qq * 4),
                        __ATOMIC_RELAXED, __HIP_MEMORY_SCOPE_AGENT);
                #pragma unroll
                for (int i = 0; i < 2; ++i) {
                    const unsigned a0 = (unsigned)(L[0] >> (32 * i));
                    const unsigned a1 = (unsigned)(L[1] >> (32 * i));
                    const unsigned a2 = (unsigned)(L[2] >> (32 * i));
                    const unsigned a3 = (unsigned)(L[3] >> (32 * i));
                    const unsigned r0w0 = (a0 & 0xFFFFu) | (a1 << 16);
                    const unsigned r0w1 = (a2 & 0xFFFFu) | (a3 << 16);
                    const unsigned r1w0 = (a0 >> 16) | (a1 & 0xFFFF0000u);
                    const unsigned r1w1 = (a2 >> 16) | (a3 & 0xFFFF0000u);
                    *(unsigned long long*)&hS[(4 * qq + 2 * i) * HSTR + 4 * cp] =
                        (unsigned long long)r0w0 | ((unsigned long long)r0w1 << 32);
                    *(unsigned long long*)&hS[(4 * qq + 2 * i + 1) * HSTR + 4 * cp] =
                        (unsigned long long)r1w0 | ((unsigned long long)r1w1 << 32);
                }
            }
        }

        __syncthreads();

        // ---- MFMA over this wave's k-half ----
        f32x4 acc = {0.f, 0.f, 0.f, 0.f};
        {
            const unsigned short* hrow = &hS[(l & 15) * HSTR + K0];
            #pragma unroll
            for (int s = 0; s < 16; ++s) {
                const bf16x8 a = *(const bf16x8*)(hrow + 32 * s + 8 * q);
                acc = __builtin_amdgcn_mfma_f32_16x16x32_bf16(a, Bhi[s], acc, 0, 0, 0);
                acc = __builtin_amdgcn_mfma_f32_16x16x32_bf16(a, Blo[s], acc, 0, 0, 0);
            }
        }

        // ---- reduce k-halves: odd waves hand partials to even waves ----
        if (w & 1) redS[(w >> 1) * 64 + l] = acc;
        __syncthreads();

        if (!(w & 1)) {
            const f32x4 p = redS[(w >> 1) * 64 + l];
            // C/D layout: col = lane&15, row = q*4 + reg
            float v0 = tanhf(acc[0] + p[0] + xpv[0]);
            float v1 = tanhf(acc[1] + p[1] + xpv[1]);
            float v2 = tanhf(acc[2] + p[2] + xpv[2]);
            float v3 = tanhf(acc[3] + p[3] + xpv[3]);

            // bf16 side-channel store FIRST (it is what gates the next step)
            const unsigned p0 = (unsigned)f2bf_rne(v0) | ((unsigned)f2bf_rne(v1) << 16);
            const unsigned p1 = (unsigned)f2bf_rne(v2) | ((unsigned)f2bf_rne(v3) << 16);
            unsigned short* gW = hX + (size_t)(t & 1) * (8 * HXGRP) + (size_t)bt * HXGRP;
            __hip_atomic_store(
                (unsigned long long*)(gW + (size_t)(cb + n) * 16 + q * 4),
                (unsigned long long)p0 | ((unsigned long long)p1 << 32),
                __ATOMIC_RELAXED, __HIP_MEMORY_SCOPE_AGENT);

            // fp32 output: plain nontemporal (nobody reads it cross-block)
            __builtin_nontemporal_store(v0, &outT[(size_t)(B0 + q * 4 + 0) * DIM + cb + n]);
            __builtin_nontemporal_store(v1, &outT[(size_t)(B0 + q * 4 + 1) * DIM + cb + n]);
            __builtin_nontemporal_store(v2, &outT[(size_t)(B0 + q * 4 + 2) * DIM + cb + n]);
            __builtin_nontemporal_store(v3, &outT[(size_t)(B0 + q * 4 + 3) * DIM + cb + n]);
        }

        // ---- fence-free PER-GROUP barrier (16 blocks sharing bt) ----
        if (t < SEQ - 1) {
            // drain my wave's stores (hX bypass + out) before arriving
            asm volatile("s_waitcnt vmcnt(0)" ::: "memory");
            __syncthreads();   // all waves' stores drained
            if (tid == 0)
                __hip_atomic_store(&flags[bid * FLAGSTR], (unsigned)(t + 1),
                                   __ATOMIC_RELAXED, __HIP_MEMORY_SCOPE_AGENT);
            // threads 0..15 each watch one block of this bt-group
            if (tid < GRP) {
                const unsigned* slot = &flags[(bt * GRP + tid) * FLAGSTR];
                while (__hip_atomic_load(slot, __ATOMIC_RELAXED,
                                         __HIP_MEMORY_SCOPE_AGENT) < (unsigned)(t + 1))
                    __builtin_amdgcn_s_sleep(2);
            }
            __syncthreads();
        }
    }
}

// ---------------------------------------------------------------------------
extern "C" void kernel_launch(void* const* d_in, const int* in_sizes, int n_in,
                              void* d_out, int out_size, void* d_ws, size_t ws_size,
                              hipStream_t stream) {
    const float* x  = (const float*)d_in[0];   // [S,B,D]
    const float* h0 = (const float*)d_in[1];   // [B,D]
    const float* Wx = (const float*)d_in[2];   // [D,D]
    const float* Wh = (const float*)d_in[3];   // [D,D]
    const float* b  = (const float*)d_in[4];   // [D]
    float* out = (float*)d_out;                // [S,B,D]
    unsigned* flags = (unsigned*)d_ws;         // 128 slots x 64 B
    unsigned short* hX = (unsigned short*)((char*)d_ws + 8192);  // 512 KB

    hipMemsetAsync(d_ws, 0, NBLK * FLAGSTR * sizeof(unsigned), stream);

    xp_pers<<<dim3(XNB), dim3(512), 0, stream>>>(x, Wx, b, out);

    rnn_scan<<<dim3(NBLK), dim3(512), 0, stream>>>(h0, Wh, out, flags, hX);
}